// Round 2
// baseline (3700.014 us; speedup 1.0000x reference)
//
#include <hip/hip_runtime.h>
#include <math.h>

// x [64,3,224,224] fp32; expert: conv3x3 s2 (3->64)+ReLU -> conv3x3 s2 (64->128)
// +ReLU -> GAP -> FC 128->2; blend on t softmax conf <= 0.9.
// SAME s2: pad_lo=0, pad_hi=1 both convs.
// Out: 129 floats = logits[64][2] + freq.
//
// ws: [0,147456) w2t[2][576][128] (k=ic*9+kh*3+kw, oc contiguous)
//     [147456,163840) g[2][64][128]

__global__ __launch_bounds__(256) void transpose_w2(
    const float* __restrict__ w2_t, const float* __restrict__ w2_f,
    float* __restrict__ w2t) {
  int idx = blockIdx.x * 256 + threadIdx.x;   // [0,147456)
  int e = idx / 73728;
  int r = idx - e * 73728;
  int k = r >> 7;
  int oc = r & 127;
  const float* src = e ? w2_f : w2_t;
  w2t[idx] = src[oc * 576 + k];
}

// Block tile: conv2 out rows {2t, 2t+1}, px 0..63 (px>=56 discarded), all 128 oc.
// h1 tile per ic: rows 4t..4t+4 (5), cols parity-split:
//   row layout [132]: even plane [0..64] (ex=hx/2, hx even 0..128), pad 65..67,
//                     odd plane at +68 [0..63] (ox=(hx-1)/2, hx odd 1..127).
// Thread: ocg=tid>>4 (8 oc), posg=tid&15 -> r=posg>>3, px0=(posg&7)*8; 64 acc.
__global__ __launch_bounds__(256, 4) void fused_expert(
    const float* __restrict__ x,
    const float* __restrict__ w1_t, const float* __restrict__ b1_t,
    const float* __restrict__ b2_t,
    const float* __restrict__ w1_f, const float* __restrict__ b1_f,
    const float* __restrict__ b2_f,
    const float* __restrict__ w2t_all,   // [2][576][128]
    float* __restrict__ g)               // [2][64][128]
{
  const int t = blockIdx.x;   // 0..27
  const int b = blockIdx.y;   // 0..63
  const int e = blockIdx.z;   // 0..1

  const float* w1  = e ? w1_f : w1_t;
  const float* b1  = e ? b1_f : b1_t;
  const float* b2  = e ? b2_f : b2_t;
  const float* w2t = w2t_all + e * 73728;

  __shared__ float h1_s[8 * 660];   // 21.1 KB: [ic_l][5][132]
  __shared__ float w1_s[1728];      // 6.9 KB

  const int tid = threadIdx.x;
  for (int i = tid; i < 1728; i += 256) w1_s[i] = w1[i];

  const int ocg = tid >> 4;          // 0..15 -> oc = ocg*8..+7
  const int posg = tid & 15;
  const int r   = posg >> 3;         // 0..1
  const int px0 = (posg & 7) * 8;    // 0,8,..,56

  float acc[8][8];                   // [oc][px]
#pragma unroll
  for (int i = 0; i < 8; ++i)
#pragma unroll
    for (int j = 0; j < 8; ++j) acc[i][j] = 0.f;

  const int hcl = tid >> 5;          // 0..7
  const int l32 = tid & 31;
  const float* xb = x + (size_t)b * 150528;

  for (int c = 0; c < 8; ++c) {
    __syncthreads();
    // ---- conv1: h1 channels c*8+hcl over rows 4t..4t+4, hx 0..128 ----
    {
      const int hc = c * 8 + hcl;
      const float bias = b1[hc];
      float wr[27];
#pragma unroll
      for (int q = 0; q < 27; ++q) wr[q] = w1_s[hc * 27 + q];
#pragma unroll
      for (int hy = 0; hy < 5; ++hy) {
        const int hyg = 4 * t + hy;
        for (int hx = l32; hx <= 128; hx += 32) {
          float v = 0.f;
          if (hyg < 112 && hx < 112) {
            float a = bias;
            const int xc = 2 * hx;
            const bool edge = (xc + 2 >= 224);    // hx==111
#pragma unroll
            for (int ic = 0; ic < 3; ++ic)
#pragma unroll
              for (int kh = 0; kh < 3; ++kh) {
                const int xr = 2 * hyg + kh;
                if (xr < 224) {
                  const float* rp = xb + (ic * 224 + xr) * 224 + xc;
                  a = fmaf(rp[0], wr[ic * 9 + kh * 3 + 0], a);
                  a = fmaf(rp[1], wr[ic * 9 + kh * 3 + 1], a);
                  a = fmaf(edge ? 0.f : rp[2], wr[ic * 9 + kh * 3 + 2], a);
                }
              }
            v = fmaxf(a, 0.f);
          }
          const int base = hcl * 660 + hy * 132;
          h1_s[base + ((hx & 1) ? 68 : 0) + (hx >> 1)] = v;
        }
      }
    }
    __syncthreads();
    // ---- conv2 partial: 8 ic x 3 kh, 192 FMA per step ----
#pragma unroll
    for (int icl = 0; icl < 8; ++icl) {
#pragma unroll
      for (int kh = 0; kh < 3; ++kh) {
        const float* hb = &h1_s[icl * 660 + (2 * r + kh) * 132 + px0];
        float he[12], ho[8];
        *(float4*)&he[0] = *(const float4*)&hb[0];
        *(float4*)&he[4] = *(const float4*)&hb[4];
        *(float4*)&he[8] = *(const float4*)&hb[8];
        *(float4*)&ho[0] = *(const float4*)&hb[68];
        *(float4*)&ho[4] = *(const float4*)&hb[72];
        const int k = (c * 8 + icl) * 9 + kh * 3;
        const float* wp = w2t + k * 128 + ocg * 8;
        {  // kw = 0: h = even[px..px+7] = he[j]
          float4 wA = *(const float4*)wp;
          float4 wB = *(const float4*)(wp + 4);
          float wv[8] = {wA.x, wA.y, wA.z, wA.w, wB.x, wB.y, wB.z, wB.w};
#pragma unroll
          for (int j = 0; j < 8; ++j)
#pragma unroll
            for (int i = 0; i < 8; ++i)
              acc[i][j] = fmaf(wv[i], he[j], acc[i][j]);
        }
        {  // kw = 1: odd[px..px+7] = ho[j]
          float4 wA = *(const float4*)(wp + 128);
          float4 wB = *(const float4*)(wp + 132);
          float wv[8] = {wA.x, wA.y, wA.z, wA.w, wB.x, wB.y, wB.z, wB.w};
#pragma unroll
          for (int j = 0; j < 8; ++j)
#pragma unroll
            for (int i = 0; i < 8; ++i)
              acc[i][j] = fmaf(wv[i], ho[j], acc[i][j]);
        }
        {  // kw = 2: even[px+1..px+8] = he[j+1]
          float4 wA = *(const float4*)(wp + 256);
          float4 wB = *(const float4*)(wp + 260);
          float wv[8] = {wA.x, wA.y, wA.z, wA.w, wB.x, wB.y, wB.z, wB.w};
#pragma unroll
          for (int j = 0; j < 8; ++j)
#pragma unroll
            for (int i = 0; i < 8; ++i)
              acc[i][j] = fmaf(wv[i], he[j + 1], acc[i][j]);
        }
      }
    }
  }

  // ---- epilogue: +b2, ReLU, pool valid px, block-reduce, atomic ----
  __syncthreads();
  float* red = h1_s;  // 16*130 = 2080 floats
#pragma unroll
  for (int i = 0; i < 8; ++i) {
    float bb = b2[ocg * 8 + i];
    float s = 0.f;
#pragma unroll
    for (int j = 0; j < 8; ++j)
      s += (px0 + j < 56) ? fmaxf(acc[i][j] + bb, 0.f) : 0.f;
    red[posg * 130 + ocg * 8 + i] = s;
  }
  __syncthreads();
  if (tid < 128) {
    float s = 0.f;
#pragma unroll
    for (int pg = 0; pg < 16; ++pg) s += red[pg * 130 + tid];
    atomicAdd(&g[(e * 64 + b) * 128 + tid], s);
  }
}

__global__ __launch_bounds__(64) void finale(
    const float* __restrict__ g,
    const float* __restrict__ t_wf, const float* __restrict__ t_bf,
    const float* __restrict__ f_wf, const float* __restrict__ f_bf,
    float* __restrict__ out)
{
  const int b = threadIdx.x;
  const float inv = 1.0f / 3136.0f;
  const float* gt = g + b * 128;
  const float* gf = g + (64 + b) * 128;
  float lt0 = t_bf[0], lt1 = t_bf[1];
  float lf0 = f_bf[0], lf1 = f_bf[1];
  for (int k = 0; k < 128; ++k) {
    float vt = gt[k] * inv;
    float vf = gf[k] * inv;
    lt0 = fmaf(vt, t_wf[2 * k],     lt0);
    lt1 = fmaf(vt, t_wf[2 * k + 1], lt1);
    lf0 = fmaf(vf, f_wf[2 * k],     lf0);
    lf1 = fmaf(vf, f_wf[2 * k + 1], lf1);
  }
  float m  = fmaxf(lt0, lt1);
  float e0 = expf(lt0 - m), e1 = expf(lt1 - m);
  float conf = fmaxf(e0, e1) / (e0 + e1);
  bool use2 = (conf <= 0.9f);
  out[2 * b]     = use2 ? 0.7f * lt0 + 0.3f * lf0 : lt0;
  out[2 * b + 1] = use2 ? 0.7f * lt1 + 0.3f * lf1 : lt1;
  unsigned long long mask = __ballot(use2);
  if (b == 0) out[128] = (float)__popcll(mask) * (1.0f / 64.0f);
}

extern "C" void kernel_launch(void* const* d_in, const int* in_sizes, int n_in,
                              void* d_out, int out_size, void* d_ws, size_t ws_size,
                              hipStream_t stream) {
  const float* x    = (const float*)d_in[0];
  const float* t_w1 = (const float*)d_in[1];
  const float* t_b1 = (const float*)d_in[2];
  const float* t_w2 = (const float*)d_in[3];
  const float* t_b2 = (const float*)d_in[4];
  const float* t_wf = (const float*)d_in[5];
  const float* t_bf = (const float*)d_in[6];
  const float* f_w1 = (const float*)d_in[7];
  const float* f_b1 = (const float*)d_in[8];
  const float* f_w2 = (const float*)d_in[9];
  const float* f_b2 = (const float*)d_in[10];
  const float* f_wf = (const float*)d_in[11];
  const float* f_bf = (const float*)d_in[12];
  float* out = (float*)d_out;

  float* w2t = (float*)d_ws;
  float* g   = w2t + 2 * 576 * 128;

  hipMemsetAsync(g, 0, 2 * 64 * 128 * sizeof(float), stream);
  transpose_w2<<<576, 256, 0, stream>>>(t_w2, f_w2, w2t);
  fused_expert<<<dim3(28, 64, 2), 256, 0, stream>>>(
      x, t_w1, t_b1, t_b2, f_w1, f_b1, f_b2, w2t, g);
  finale<<<1, 64, 0, stream>>>(g, t_wf, t_bf, f_wf, f_bf, out);
}

// Round 3
// 1150.001 us; speedup vs baseline: 3.2174x; 3.2174x over previous
//
#include <hip/hip_runtime.h>
#include <math.h>

// x [64,3,224,224] fp32; expert: conv3x3 s2 (3->64)+ReLU -> conv3x3 s2 (64->128)
// +ReLU -> GAP -> FC 128->2; blend on t softmax conf <= 0.9.
// SAME s2: pad_lo=0, pad_hi=1 both convs. Out: 129 floats.
//
// ws layout (floats):
//   W2T_OFF: w2t[2][576][128]   (k=ic*9+kh*3+kw, oc contiguous)
//   W1T_OFF: w1t[2][27][64]     (k=ic*9+kh*3+kw, ch contiguous)
//   G_OFF:   g[2][64][128]      pooled un-normalized relu sums
//   H1_OFF:  h1[64 b][64 ch][113 row][120]  (one expert at a time)
//            row layout: even plane [0..56] (idx=hx/2, hx even, idx 56 = pad 0),
//            pad [57..59], odd plane [60..115] (idx=(hx-1)/2), pad [116..119].
//            row 112 = zeros (conv2 SAME pad row).

#define W2T_OFF 0
#define W1T_OFF 147456
#define G_OFF   150912
#define H1_OFF  167424
#define H1_FLOATS (64LL * 64 * 113 * 120)

__global__ __launch_bounds__(256) void prep_weights(
    const float* __restrict__ w2_t, const float* __restrict__ w2_f,
    const float* __restrict__ w1_t, const float* __restrict__ w1_f,
    float* __restrict__ ws) {
  int idx = blockIdx.x * 256 + threadIdx.x;
  if (idx < 147456) {
    int e = idx / 73728;
    int r = idx - e * 73728;
    int k = r >> 7, oc = r & 127;
    const float* src = e ? w2_f : w2_t;
    ws[W2T_OFF + idx] = src[oc * 576 + k];
  } else if (idx < 150912) {
    int i2 = idx - 147456;
    int e = i2 / 1728;
    int r = i2 - e * 1728;
    int k = r >> 6, ch = r & 63;
    const float* src = e ? w1_f : w1_t;
    ws[W1T_OFF + i2] = src[ch * 27 + k];
  }
}

// conv1: one block per (h1 row, batch). Thread: 4 ch x 8 hx, 32 acc.
// x staged parity-split in LDS so inner loop is pure b128 + FMA.
__global__ __launch_bounds__(256, 2) void conv1_kernel(
    const float* __restrict__ x,
    const float* __restrict__ w1t,   // [27][64] this expert
    const float* __restrict__ b1,
    float* __restrict__ h1)          // [64][64][113][120]
{
  const int row = blockIdx.x;   // 0..112
  const int b   = blockIdx.y;
  const int tid = threadIdx.x;
  float* h1b = h1 + (size_t)b * (64 * 113 * 120);

  if (row == 112) {  // conv2's SAME pad row: zeros for all 64 ch
    float4 z = {0.f, 0.f, 0.f, 0.f};
    for (int i = tid; i < 64 * 30; i += 256) {
      int ch = i / 30, f = i - ch * 30;
      *(float4*)(h1b + ((size_t)ch * 113 + 112) * 120 + f * 4) = z;
    }
    return;
  }

  __shared__ float x_s[2112];   // [9][232]: even [0..112], odd at 116 [0..111]
  __shared__ float w1s[1728];   // [27][64]

  for (int i = tid; i < 1728; i += 256) w1s[i] = w1t[i];
  const float* xb = x + (size_t)b * 150528;
  for (int i = tid; i < 9 * 113; i += 256) {
    int ickr = i / 113;           // ic*3+kr
    int col  = i - ickr * 113;    // 0..112
    int xr = 2 * row + (ickr % 3);
    float e0 = 0.f, o0 = 0.f;
    if (xr < 224 && col < 112) {
      const float* p = xb + ((ickr / 3) * 224 + xr) * 224 + 2 * col;
      e0 = p[0]; o0 = p[1];
    }
    x_s[ickr * 232 + col] = e0;
    x_s[ickr * 232 + 116 + col] = o0;   // col 112 -> offset 228 pad, harmless
  }
  __syncthreads();

  const int chg = tid >> 4;      // ch0 = chg*4
  const int pxg = tid & 15;      // hx0 = pxg*8
  const int hx0 = pxg * 8;

  float acc[4][8];
#pragma unroll
  for (int c = 0; c < 4; ++c)
#pragma unroll
    for (int j = 0; j < 8; ++j) acc[c][j] = 0.f;

#pragma unroll
  for (int ickr = 0; ickr < 9; ++ickr) {
    const float* xs = &x_s[ickr * 232];
    float he[12], ho[8];
    *(float4*)&he[0] = *(const float4*)&xs[hx0];
    *(float4*)&he[4] = *(const float4*)&xs[hx0 + 4];
    *(float4*)&he[8] = *(const float4*)&xs[hx0 + 8];
    *(float4*)&ho[0] = *(const float4*)&xs[116 + hx0];
    *(float4*)&ho[4] = *(const float4*)&xs[116 + hx0 + 4];
    const float4 w0 = *(const float4*)&w1s[(ickr * 3 + 0) * 64 + chg * 4];
    const float4 w1v = *(const float4*)&w1s[(ickr * 3 + 1) * 64 + chg * 4];
    const float4 w2v = *(const float4*)&w1s[(ickr * 3 + 2) * 64 + chg * 4];
    float wa[4] = {w0.x, w0.y, w0.z, w0.w};
    float wb[4] = {w1v.x, w1v.y, w1v.z, w1v.w};
    float wc[4] = {w2v.x, w2v.y, w2v.z, w2v.w};
#pragma unroll
    for (int j = 0; j < 8; ++j)
#pragma unroll
      for (int c = 0; c < 4; ++c) {
        acc[c][j] = fmaf(wa[c], he[j], acc[c][j]);
        acc[c][j] = fmaf(wb[c], ho[j], acc[c][j]);
        acc[c][j] = fmaf(wc[c], he[j + 1], acc[c][j]);
      }
  }

  if (pxg < 15) {   // pxg 15 (hx 120..127) would collide with odd plane
    const float4 bb = *(const float4*)&b1[chg * 4];
    float bv[4] = {bb.x, bb.y, bb.z, bb.w};
#pragma unroll
    for (int c = 0; c < 4; ++c) {
      float v[8];
#pragma unroll
      for (int j = 0; j < 8; ++j) {
        float t = fmaxf(acc[c][j] + bv[c], 0.f);
        v[j] = (hx0 + j < 112) ? t : 0.f;   // col pad (incl. even idx 56)
      }
      float* rowp = h1b + ((size_t)(chg * 4 + c) * 113 + row) * 120;
      float4 ev = {v[0], v[2], v[4], v[6]};
      float4 od = {v[1], v[3], v[5], v[7]};
      *(float4*)(rowp + pxg * 4) = ev;
      *(float4*)(rowp + 60 + pxg * 4) = od;
    }
  }
}

// conv2: one block per (2 out rows, batch). Thread: 8 oc x 8 px, 64 acc.
__global__ __launch_bounds__(256, 2) void conv2_kernel(
    const float* __restrict__ h1,    // [64][64][113][120]
    const float* __restrict__ w2t,   // [576][128] this expert
    const float* __restrict__ b2,
    float* __restrict__ g)           // [64][128] this expert
{
  const int t = blockIdx.x;   // 0..27
  const int b = blockIdx.y;
  const int tid = threadIdx.x;

  __shared__ float hc[4816];        // [8 ic][5 row][120] + OOB pad
  __shared__ float red[16 * 130];

  const int ocg  = tid >> 4;        // oc0 = ocg*8
  const int posg = tid & 15;
  const int r    = posg >> 3;       // out row 2t + r
  const int px0  = (posg & 7) * 8;  // px >= 56 discarded

  float acc[8][8];
#pragma unroll
  for (int i = 0; i < 8; ++i)
#pragma unroll
    for (int j = 0; j < 8; ++j) acc[i][j] = 0.f;

  const float* h1b = h1 + (size_t)b * (64 * 113 * 120);

  for (int c = 0; c < 8; ++c) {
    __syncthreads();
    for (int i = tid; i < 1200; i += 256) {   // 8 ic x 5 rows x 30 float4
      int lic = i / 150;
      int r2 = i - lic * 150;
      int lr = r2 / 30, f = r2 - lr * 30;
      *(float4*)&hc[(lic * 5 + lr) * 120 + f * 4] =
          *(const float4*)&h1b[((size_t)(c * 8 + lic) * 113 + 4 * t + lr) * 120 + f * 4];
    }
    __syncthreads();
    for (int icl = 0; icl < 8; ++icl) {
      const float* wp_ic = w2t + (size_t)((c * 8 + icl) * 9) * 128 + ocg * 8;
#pragma unroll
      for (int kh = 0; kh < 3; ++kh) {
        const float* hb = &hc[(icl * 5 + 2 * r + kh) * 120 + px0];
        float he[12], ho[8];
        *(float4*)&he[0] = *(const float4*)&hb[0];
        *(float4*)&he[4] = *(const float4*)&hb[4];
        *(float4*)&he[8] = *(const float4*)&hb[8];
        *(float4*)&ho[0] = *(const float4*)&hb[60];
        *(float4*)&ho[4] = *(const float4*)&hb[64];
        const float* wp = wp_ic + kh * 3 * 128;
        {  // kw=0: even[px]
          float4 wA = *(const float4*)wp;
          float4 wB = *(const float4*)(wp + 4);
          float wv[8] = {wA.x, wA.y, wA.z, wA.w, wB.x, wB.y, wB.z, wB.w};
#pragma unroll
          for (int j = 0; j < 8; ++j)
#pragma unroll
            for (int i = 0; i < 8; ++i)
              acc[i][j] = fmaf(wv[i], he[j], acc[i][j]);
        }
        {  // kw=1: odd[px]
          float4 wA = *(const float4*)(wp + 128);
          float4 wB = *(const float4*)(wp + 132);
          float wv[8] = {wA.x, wA.y, wA.z, wA.w, wB.x, wB.y, wB.z, wB.w};
#pragma unroll
          for (int j = 0; j < 8; ++j)
#pragma unroll
            for (int i = 0; i < 8; ++i)
              acc[i][j] = fmaf(wv[i], ho[j], acc[i][j]);
        }
        {  // kw=2: even[px+1]
          float4 wA = *(const float4*)(wp + 256);
          float4 wB = *(const float4*)(wp + 260);
          float wv[8] = {wA.x, wA.y, wA.z, wA.w, wB.x, wB.y, wB.z, wB.w};
#pragma unroll
          for (int j = 0; j < 8; ++j)
#pragma unroll
            for (int i = 0; i < 8; ++i)
              acc[i][j] = fmaf(wv[i], he[j + 1], acc[i][j]);
        }
      }
    }
  }

  __syncthreads();
  {
    const float4 bA = *(const float4*)&b2[ocg * 8];
    const float4 bB = *(const float4*)&b2[ocg * 8 + 4];
    float bv[8] = {bA.x, bA.y, bA.z, bA.w, bB.x, bB.y, bB.z, bB.w};
#pragma unroll
    for (int i = 0; i < 8; ++i) {
      float s = 0.f;
#pragma unroll
      for (int j = 0; j < 8; ++j)
        s += (px0 + j < 56) ? fmaxf(acc[i][j] + bv[i], 0.f) : 0.f;
      red[posg * 130 + ocg * 8 + i] = s;
    }
  }
  __syncthreads();
  if (tid < 128) {
    float s = 0.f;
#pragma unroll
    for (int pg = 0; pg < 16; ++pg) s += red[pg * 130 + tid];
    atomicAdd(&g[b * 128 + tid], s);
  }
}

// -------- fallback (ws too small): round-1 fused kernel, known-correct --------
__global__ __launch_bounds__(256, 3) void fused_expert(
    const float* __restrict__ x,
    const float* __restrict__ w1_t, const float* __restrict__ b1_t,
    const float* __restrict__ b2_t,
    const float* __restrict__ w1_f, const float* __restrict__ b1_f,
    const float* __restrict__ b2_f,
    const float* __restrict__ w2t_all, float* __restrict__ g)
{
  const int tile = blockIdx.x, b = blockIdx.y, e = blockIdx.z;
  const int ty = tile >> 1, tx = tile & 1;
  const float* w1  = e ? w1_f : w1_t;
  const float* b1  = e ? b1_f : b1_t;
  const float* b2  = e ? b2_f : b2_t;
  const float* w2t = w2t_all + e * 73728;
  __shared__ float x_s[3 * 19 * 116];
  __shared__ float h1_s[8 * 9 * 58];
  __shared__ float w1_s[1728];
  const int tid = threadIdx.x;
  {
    const float* xb = x + (size_t)b * 150528;
    const int xr0 = ty * 16, xc0 = tx * 112;
    for (int idx = tid; idx < 3 * 19 * 116; idx += 256) {
      int ic = idx / (19 * 116);
      int rem = idx - ic * (19 * 116);
      int r = rem / 116, cc = rem - r * 116;
      int xr = xr0 + r, xc = xc0 + cc;
      float v = 0.f;
      if (xr < 224 && xc < 224 && cc < 115) v = xb[(ic * 224 + xr) * 224 + xc];
      x_s[idx] = v;
    }
    for (int idx = tid; idx < 1728; idx += 256) w1_s[idx] = w1[idx];
  }
  const int ocg = tid >> 4, posg = tid & 15;
  int pbase[7];
#pragma unroll
  for (int j = 0; j < 7; ++j) {
    int p = posg + 16 * j, py = p / 28, px = p - py * 28;
    pbase[j] = py * 2 * 58 + px * 2;
  }
  float acc[7][8];
#pragma unroll
  for (int j = 0; j < 7; ++j)
#pragma unroll
    for (int i = 0; i < 8; ++i) acc[j][i] = 0.f;
  const int hc_l = tid >> 5, l32 = tid & 31;
  for (int c = 0; c < 8; ++c) {
    __syncthreads();
    {
      const int hc = c * 8 + hc_l;
      const float bias = b1[hc];
      float wr[27];
#pragma unroll
      for (int q = 0; q < 27; ++q) wr[q] = w1_s[hc * 27 + q];
      for (int p = l32; p < 513; p += 32) {
        int hy = p / 57, hx = p - hy * 57;
        float a = bias;
#pragma unroll
        for (int ic = 0; ic < 3; ++ic)
#pragma unroll
          for (int kh = 0; kh < 3; ++kh) {
            const float* row = &x_s[ic * (19 * 116) + (2 * hy + kh) * 116 + 2 * hx];
            a = fmaf(row[0], wr[ic * 9 + kh * 3 + 0], a);
            a = fmaf(row[1], wr[ic * 9 + kh * 3 + 1], a);
            a = fmaf(row[2], wr[ic * 9 + kh * 3 + 2], a);
          }
        float v = fmaxf(a, 0.f);
        int hy_g = ty * 8 + hy, hx_g = tx * 56 + hx;
        if (hy_g >= 112 || hx_g >= 112) v = 0.f;
        h1_s[hc_l * 522 + hy * 58 + hx] = v;
      }
    }
    __syncthreads();
    for (int ic_l = 0; ic_l < 8; ++ic_l) {
#pragma unroll
      for (int kh = 0; kh < 3; ++kh)
#pragma unroll
        for (int kw = 0; kw < 3; ++kw) {
          const int k = (c * 8 + ic_l) * 9 + kh * 3 + kw;
          const float4 wA = *(const float4*)(w2t + k * 128 + ocg * 8);
          const float4 wB = *(const float4*)(w2t + k * 128 + ocg * 8 + 4);
          const float* hp = &h1_s[ic_l * 522 + kh * 58 + kw];
#pragma unroll
          for (int j = 0; j < 7; ++j) {
            float h = hp[pbase[j]];
            acc[j][0] = fmaf(wA.x, h, acc[j][0]);
            acc[j][1] = fmaf(wA.y, h, acc[j][1]);
            acc[j][2] = fmaf(wA.z, h, acc[j][2]);
            acc[j][3] = fmaf(wA.w, h, acc[j][3]);
            acc[j][4] = fmaf(wB.x, h, acc[j][4]);
            acc[j][5] = fmaf(wB.y, h, acc[j][5]);
            acc[j][6] = fmaf(wB.z, h, acc[j][6]);
            acc[j][7] = fmaf(wB.w, h, acc[j][7]);
          }
        }
    }
  }
  __syncthreads();
  float* red = x_s;
#pragma unroll
  for (int i = 0; i < 8; ++i) {
    float bb = b2[ocg * 8 + i];
    float t = 0.f;
#pragma unroll
    for (int j = 0; j < 7; ++j) t += fmaxf(acc[j][i] + bb, 0.f);
    red[posg * 129 + ocg * 8 + i] = t;
  }
  __syncthreads();
  if (tid < 128) {
    float t = 0.f;
#pragma unroll
    for (int pg = 0; pg < 16; ++pg) t += red[pg * 129 + tid];
    atomicAdd(&g[(e * 64 + b) * 128 + tid], t);
  }
}

__global__ __launch_bounds__(64) void finale(
    const float* __restrict__ g,
    const float* __restrict__ t_wf, const float* __restrict__ t_bf,
    const float* __restrict__ f_wf, const float* __restrict__ f_bf,
    float* __restrict__ out)
{
  const int b = threadIdx.x;
  const float inv = 1.0f / 3136.0f;
  const float* gt = g + b * 128;
  const float* gf = g + (64 + b) * 128;
  float lt0 = t_bf[0], lt1 = t_bf[1];
  float lf0 = f_bf[0], lf1 = f_bf[1];
  for (int k = 0; k < 128; ++k) {
    float vt = gt[k] * inv;
    float vf = gf[k] * inv;
    lt0 = fmaf(vt, t_wf[2 * k],     lt0);
    lt1 = fmaf(vt, t_wf[2 * k + 1], lt1);
    lf0 = fmaf(vf, f_wf[2 * k],     lf0);
    lf1 = fmaf(vf, f_wf[2 * k + 1], lf1);
  }
  float m  = fmaxf(lt0, lt1);
  float e0 = expf(lt0 - m), e1 = expf(lt1 - m);
  float conf = fmaxf(e0, e1) / (e0 + e1);
  bool use2 = (conf <= 0.9f);
  out[2 * b]     = use2 ? 0.7f * lt0 + 0.3f * lf0 : lt0;
  out[2 * b + 1] = use2 ? 0.7f * lt1 + 0.3f * lf1 : lt1;
  unsigned long long mask = __ballot(use2);
  if (b == 0) out[128] = (float)__popcll(mask) * (1.0f / 64.0f);
}

extern "C" void kernel_launch(void* const* d_in, const int* in_sizes, int n_in,
                              void* d_out, int out_size, void* d_ws, size_t ws_size,
                              hipStream_t stream) {
  const float* x    = (const float*)d_in[0];
  const float* t_w1 = (const float*)d_in[1];
  const float* t_b1 = (const float*)d_in[2];
  const float* t_w2 = (const float*)d_in[3];
  const float* t_b2 = (const float*)d_in[4];
  const float* t_wf = (const float*)d_in[5];
  const float* t_bf = (const float*)d_in[6];
  const float* f_w1 = (const float*)d_in[7];
  const float* f_b1 = (const float*)d_in[8];
  const float* f_w2 = (const float*)d_in[9];
  const float* f_b2 = (const float*)d_in[10];
  const float* f_wf = (const float*)d_in[11];
  const float* f_bf = (const float*)d_in[12];
  float* out = (float*)d_out;

  float* ws  = (float*)d_ws;
  float* w2t = ws + W2T_OFF;
  float* w1t = ws + W1T_OFF;
  float* g   = ws + G_OFF;
  float* h1  = ws + H1_OFF;

  hipMemsetAsync(g, 0, 2 * 64 * 128 * sizeof(float), stream);
  prep_weights<<<590, 256, 0, stream>>>(t_w2, f_w2, t_w1, f_w1, ws);

  const size_t need = (size_t)(H1_OFF + H1_FLOATS) * sizeof(float);
  if (ws_size >= need) {
    // expert 0 (texture)
    conv1_kernel<<<dim3(113, 64), 256, 0, stream>>>(x, w1t, t_b1, h1);
    conv2_kernel<<<dim3(28, 64), 256, 0, stream>>>(h1, w2t, t_b2, g);
    // expert 1 (frequency)
    conv1_kernel<<<dim3(113, 64), 256, 0, stream>>>(x, w1t + 1728, f_b1, h1);
    conv2_kernel<<<dim3(28, 64), 256, 0, stream>>>(h1, w2t + 73728, f_b2, g + 64 * 128);
  } else {
    fused_expert<<<dim3(28, 64, 2), 256, 0, stream>>>(
        x, t_w1, t_b1, t_b2, f_w1, f_b1, f_b2, w2t, g);
  }
  finale<<<1, 64, 0, stream>>>(g, t_wf, t_bf, f_wf, f_bf, out);
}

// Round 4
// 534.532 us; speedup vs baseline: 6.9220x; 2.1514x over previous
//
#include <hip/hip_runtime.h>
#include <hip/hip_bf16.h>
#include <math.h>

// x [64,3,224,224] fp32; expert: conv3x3 s2 (3->64)+ReLU -> conv3x3 s2 (64->128)
// +ReLU -> GAP -> FC 128->2; blend on t softmax conf <= 0.9. Out: 129 floats.
// SAME s2: pad_lo=0, pad_hi=1 both convs.
//
// Round-4 scheme: conv2 via bf16 MFMA (16x16x32). Weights split hi+lo bf16
// (2 K-passes) for precision; h1 stored channel-last bf16 so B-fragments are
// single 16B reads. conv1 stays fp32 VALU, writes bf16 channel-last.
//
// ws layout (bytes):
//   W2B_OFF: ushort w2b[2 term][2 e][128 oc][576 k']   k' = kh*192+kw*64+ic
//   W1T_OFF: float  w1t[2 e][27 k][64 ch]              k  = ic*9+kh*3+kw
//   G_OFF:   float  g[2 e][64 b][128 oc]
//   H1_OFF:  ushort h1[2 e][64 b][113 row][113 hx][64 ic]  (row/col 112 = zeros)

#define W2B_OFF   0ull
#define W1T_OFF   589824ull
#define G_OFF     603648ull
#define H1_OFF    669440ull
#define H1E_US    52301824ull   // 64*113*113*64
#define H1B_US    817216ull     // 113*113*64
#define WS_NEED   (H1_OFF + 2ull*H1E_US*2ull + 4096ull)

typedef __attribute__((ext_vector_type(8))) short bf16x8;
typedef __attribute__((ext_vector_type(4))) float f32x4;

__device__ inline ushort f2bf(float v) {
  __hip_bfloat16 h = __float2bfloat16(v);
  return *(ushort*)&h;
}
__device__ inline float bf2f(ushort u) {
  __hip_bfloat16 h = *(__hip_bfloat16*)&u;
  return __bfloat162float(h);
}

__global__ __launch_bounds__(256) void prep_new(
    const float* __restrict__ w2_t, const float* __restrict__ w2_f,
    const float* __restrict__ w1_t, const float* __restrict__ w1_f,
    char* __restrict__ ws) {
  int idx = blockIdx.x * 256 + threadIdx.x;
  ushort* w2b = (ushort*)(ws + W2B_OFF);
  float* w1t = (float*)(ws + W1T_OFF);
  if (idx < 147456) {
    int e = idx / 73728;
    int r = idx - e * 73728;
    int oc = r / 576;
    int kp = r - oc * 576;
    int kh = kp / 192, r2 = kp - kh * 192, kw = r2 >> 6, ic = r2 & 63;
    const float* src = e ? w2_f : w2_t;
    float w = src[((oc * 64 + ic) * 3 + kh) * 3 + kw];
    ushort hi = f2bf(w);
    float lo = w - bf2f(hi);
    w2b[((size_t)(0 * 2 + e) * 128 + oc) * 576 + kp] = hi;
    w2b[((size_t)(1 * 2 + e) * 128 + oc) * 576 + kp] = f2bf(lo);
  } else if (idx < 147456 + 3456) {
    int i2 = idx - 147456;
    int e = i2 / 1728;
    int r = i2 - e * 1728;
    int k = r >> 6, ch = r & 63;
    const float* src = e ? w1_f : w1_t;
    w1t[i2] = src[ch * 27 + k];
  }
}

// conv1: block (row 0..112, b, e). Thread: chg=tid&15 (4 ch), pxg=tid>>4 (8 hx).
// Writes h1 channel-last bf16. Row 112 / col 112 = zeros (conv2 SAME pad).
__global__ __launch_bounds__(256, 2) void conv1_cl(
    const float* __restrict__ x,
    const float* __restrict__ w1t_all,
    const float* __restrict__ b1_t, const float* __restrict__ b1_f,
    ushort* __restrict__ h1_all)
{
  const int row = blockIdx.x;
  const int b   = blockIdx.y;
  const int e   = blockIdx.z;
  const int tid = threadIdx.x;
  ushort* h1b = h1_all + (size_t)e * H1E_US + (size_t)b * H1B_US;

  if (row == 112) {
    bf16x8 z = 0;
    for (int i = tid; i < 904; i += 256) {
      int hx = i >> 3, gq = i & 7;
      *(bf16x8*)&h1b[((size_t)(112 * 113 + hx)) * 64 + 8 * gq] = z;
    }
    return;
  }

  __shared__ float x_s[2112];   // [9][232]: even [0..112], odd at +116
  __shared__ float w1s[1728];   // [27][64]
  const float* w1t = w1t_all + e * 1728;
  const float* b1  = e ? b1_f : b1_t;
  for (int i = tid; i < 1728; i += 256) w1s[i] = w1t[i];
  const float* xb = x + (size_t)b * 150528;
  for (int i = tid; i < 9 * 113; i += 256) {
    int ickr = i / 113, col = i - ickr * 113;
    int xr = 2 * row + (ickr % 3);
    float e0 = 0.f, o0 = 0.f;
    if (xr < 224 && col < 112) {
      const float* p = xb + ((ickr / 3) * 224 + xr) * 224 + 2 * col;
      e0 = p[0]; o0 = p[1];
    }
    x_s[ickr * 232 + col] = e0;
    x_s[ickr * 232 + 116 + col] = o0;
  }
  __syncthreads();

  const int chg = tid & 15;     // lanes 0-15 span channels -> coalesced store
  const int pxg = tid >> 4;
  const int hx0 = pxg * 8;

  float acc[4][8];
#pragma unroll
  for (int c = 0; c < 4; ++c)
#pragma unroll
    for (int j = 0; j < 8; ++j) acc[c][j] = 0.f;

#pragma unroll
  for (int ickr = 0; ickr < 9; ++ickr) {
    const float* xs = &x_s[ickr * 232];
    float he[12], ho[8];
    *(float4*)&he[0] = *(const float4*)&xs[hx0];
    *(float4*)&he[4] = *(const float4*)&xs[hx0 + 4];
    *(float4*)&he[8] = *(const float4*)&xs[hx0 + 8];
    *(float4*)&ho[0] = *(const float4*)&xs[116 + hx0];
    *(float4*)&ho[4] = *(const float4*)&xs[116 + hx0 + 4];
    const float4 w0  = *(const float4*)&w1s[(ickr * 3 + 0) * 64 + chg * 4];
    const float4 w1v = *(const float4*)&w1s[(ickr * 3 + 1) * 64 + chg * 4];
    const float4 w2v = *(const float4*)&w1s[(ickr * 3 + 2) * 64 + chg * 4];
    float wa[4] = {w0.x, w0.y, w0.z, w0.w};
    float wb[4] = {w1v.x, w1v.y, w1v.z, w1v.w};
    float wc[4] = {w2v.x, w2v.y, w2v.z, w2v.w};
#pragma unroll
    for (int j = 0; j < 8; ++j)
#pragma unroll
      for (int c = 0; c < 4; ++c) {
        acc[c][j] = fmaf(wa[c], he[j], acc[c][j]);
        acc[c][j] = fmaf(wb[c], ho[j], acc[c][j]);
        acc[c][j] = fmaf(wc[c], he[j + 1], acc[c][j]);
      }
  }

  const float4 bb = *(const float4*)&b1[chg * 4];
  float bv[4] = {bb.x, bb.y, bb.z, bb.w};
#pragma unroll
  for (int j = 0; j < 8; ++j) {
    int hx = hx0 + j;
    if (hx < 113) {
      ushort v4[4];
#pragma unroll
      for (int c = 0; c < 4; ++c) {
        float t = (hx < 112) ? fmaxf(acc[c][j] + bv[c], 0.f) : 0.f;
        v4[c] = f2bf(t);
      }
      uint2 u;
      u.x = (uint)v4[0] | ((uint)v4[1] << 16);
      u.y = (uint)v4[2] | ((uint)v4[3] << 16);
      *(uint2*)&h1b[((size_t)(row * 113 + hx)) * 64 + chg * 4] = u;
    }
  }
}

// conv2 via MFMA. Block (T=row-pair 0..27, b, e), 4 waves.
// Wave w: oc tiles {2w,2w+1} (32 oc), 7 N-tiles (8px x 2rows = 112 px exact).
// K' = kh*192+kw*64+ic, chunks of 32; terms hi/lo of w2.
__global__ __launch_bounds__(256) void conv2_mfma(
    const ushort* __restrict__ h1_all,
    const ushort* __restrict__ w2b,
    const float* __restrict__ b2_t, const float* __restrict__ b2_f,
    float* __restrict__ g)
{
  const int T = blockIdx.x;
  const int b = blockIdx.y;
  const int e = blockIdx.z;
  const int tid  = threadIdx.x;
  const int w    = tid >> 6;
  const int lane = tid & 63;
  const ushort* h1b = h1_all + (size_t)e * H1E_US + (size_t)b * H1B_US;
  const float* b2 = e ? b2_f : b2_t;

  __shared__ ushort hs[2 * 113 * 72];   // 32.5 KB, 2 staged h1 rows, ic pad 64->72

  const int q   = lane >> 4;        // k-quad
  const int n   = lane & 15;        // B col / A row
  const int pxl = lane & 7;
  const int rl  = (lane >> 3) & 1;

  f32x4 acc[2][7];
#pragma unroll
  for (int mt = 0; mt < 2; ++mt)
#pragma unroll
    for (int nt = 0; nt < 7; ++nt) acc[mt][nt] = (f32x4){0.f, 0.f, 0.f, 0.f};

  for (int kh = 0; kh < 3; ++kh) {
    __syncthreads();
    // stage h1 rows 4T+kh (r=0) and 4T+kh+2 (r=1)
    for (int i = tid; i < 1808; i += 256) {
      int rs = (i >= 904) ? 1 : 0;
      int rem = i - rs * 904;
      int hx = rem >> 3, gq = rem & 7;
      int R = 4 * T + kh + 2 * rs;
      *(bf16x8*)&hs[(rs * 113 + hx) * 72 + 8 * gq] =
          *(const bf16x8*)&h1b[((size_t)(R * 113 + hx)) * 64 + 8 * gq];
    }
    __syncthreads();
#pragma unroll
    for (int kw = 0; kw < 3; ++kw) {
#pragma unroll
      for (int icc = 0; icc < 2; ++icc) {
        const int kb = kh * 192 + kw * 64 + icc * 32;
        const int icoff = icc * 32 + 8 * q;
        bf16x8 bf[7];
#pragma unroll
        for (int nt = 0; nt < 7; ++nt) {
          int hx = 2 * (8 * nt + pxl) + kw;
          bf[nt] = *(const bf16x8*)&hs[(rl * 113 + hx) * 72 + icoff];
        }
#pragma unroll
        for (int term = 0; term < 2; ++term) {
#pragma unroll
          for (int mt = 0; mt < 2; ++mt) {
            const int oc = 32 * w + 16 * mt + n;
            bf16x8 af = *(const bf16x8*)
                &w2b[((size_t)((term * 2 + e) * 128 + oc)) * 576 + kb + 8 * q];
#pragma unroll
            for (int nt = 0; nt < 7; ++nt)
              acc[mt][nt] = __builtin_amdgcn_mfma_f32_16x16x32_bf16(
                  af, bf[nt], acc[mt][nt], 0, 0, 0);
          }
        }
      }
    }
  }

  // epilogue: +b2, ReLU, sum over this block's 112 px, atomic into g
#pragma unroll
  for (int mt = 0; mt < 2; ++mt) {
#pragma unroll
    for (int reg = 0; reg < 4; ++reg) {
      const int oc = 32 * w + 16 * mt + 4 * q + reg;
      const float bias = b2[oc];
      float s = 0.f;
#pragma unroll
      for (int nt = 0; nt < 7; ++nt) s += fmaxf(acc[mt][nt][reg] + bias, 0.f);
      s += __shfl_xor(s, 1);
      s += __shfl_xor(s, 2);
      s += __shfl_xor(s, 4);
      s += __shfl_xor(s, 8);
      if (n == 0) atomicAdd(&g[((size_t)e * 64 + b) * 128 + oc], s);
    }
  }
}

__global__ __launch_bounds__(64) void finale(
    const float* __restrict__ g,
    const float* __restrict__ t_wf, const float* __restrict__ t_bf,
    const float* __restrict__ f_wf, const float* __restrict__ f_bf,
    float* __restrict__ out)
{
  const int b = threadIdx.x;
  const float inv = 1.0f / 3136.0f;
  const float* gt = g + b * 128;
  const float* gf = g + (64 + b) * 128;
  float lt0 = t_bf[0], lt1 = t_bf[1];
  float lf0 = f_bf[0], lf1 = f_bf[1];
  for (int k = 0; k < 128; ++k) {
    float vt = gt[k] * inv;
    float vf = gf[k] * inv;
    lt0 = fmaf(vt, t_wf[2 * k],     lt0);
    lt1 = fmaf(vt, t_wf[2 * k + 1], lt1);
    lf0 = fmaf(vf, f_wf[2 * k],     lf0);
    lf1 = fmaf(vf, f_wf[2 * k + 1], lf1);
  }
  float m  = fmaxf(lt0, lt1);
  float e0 = expf(lt0 - m), e1 = expf(lt1 - m);
  float conf = fmaxf(e0, e1) / (e0 + e1);
  bool use2 = (conf <= 0.9f);
  out[2 * b]     = use2 ? 0.7f * lt0 + 0.3f * lf0 : lt0;
  out[2 * b + 1] = use2 ? 0.7f * lt1 + 0.3f * lf1 : lt1;
  unsigned long long mask = __ballot(use2);
  if (b == 0) out[128] = (float)__popcll(mask) * (1.0f / 64.0f);
}

// ---------------- fallback (ws too small): round-1 fused fp32 ----------------
__global__ __launch_bounds__(256) void transpose_w2(
    const float* __restrict__ w2_t, const float* __restrict__ w2_f,
    float* __restrict__ w2t) {
  int idx = blockIdx.x * 256 + threadIdx.x;
  int e = idx / 73728;
  int r = idx - e * 73728;
  int k = r >> 7, oc = r & 127;
  const float* src = e ? w2_f : w2_t;
  w2t[idx] = src[oc * 576 + k];
}

__global__ __launch_bounds__(256, 3) void fused_expert(
    const float* __restrict__ x,
    const float* __restrict__ w1_t, const float* __restrict__ b1_t,
    const float* __restrict__ b2_t,
    const float* __restrict__ w1_f, const float* __restrict__ b1_f,
    const float* __restrict__ b2_f,
    const float* __restrict__ w2t_all, float* __restrict__ g)
{
  const int tile = blockIdx.x, b = blockIdx.y, e = blockIdx.z;
  const int ty = tile >> 1, tx = tile & 1;
  const float* w1  = e ? w1_f : w1_t;
  const float* b1  = e ? b1_f : b1_t;
  const float* b2  = e ? b2_f : b2_t;
  const float* w2t = w2t_all + e * 73728;
  __shared__ float x_s[3 * 19 * 116];
  __shared__ float h1_s[8 * 9 * 58];
  __shared__ float w1_s[1728];
  const int tid = threadIdx.x;
  {
    const float* xb = x + (size_t)b * 150528;
    const int xr0 = ty * 16, xc0 = tx * 112;
    for (int idx = tid; idx < 3 * 19 * 116; idx += 256) {
      int ic = idx / (19 * 116);
      int rem = idx - ic * (19 * 116);
      int r = rem / 116, cc = rem - r * 116;
      int xr = xr0 + r, xc = xc0 + cc;
      float v = 0.f;
      if (xr < 224 && xc < 224 && cc < 115) v = xb[(ic * 224 + xr) * 224 + xc];
      x_s[idx] = v;
    }
    for (int idx = tid; idx < 1728; idx += 256) w1_s[idx] = w1[idx];
  }
  const int ocg = tid >> 4, posg = tid & 15;
  int pbase[7];
#pragma unroll
  for (int j = 0; j < 7; ++j) {
    int p = posg + 16 * j, py = p / 28, px = p - py * 28;
    pbase[j] = py * 2 * 58 + px * 2;
  }
  float acc[7][8];
#pragma unroll
  for (int j = 0; j < 7; ++j)
#pragma unroll
    for (int i = 0; i < 8; ++i) acc[j][i] = 0.f;
  const int hc_l = tid >> 5, l32 = tid & 31;
  for (int c = 0; c < 8; ++c) {
    __syncthreads();
    {
      const int hc = c * 8 + hc_l;
      const float bias = b1[hc];
      float wr[27];
#pragma unroll
      for (int qq = 0; qq < 27; ++qq) wr[qq] = w1_s[hc * 27 + qq];
      for (int p = l32; p < 513; p += 32) {
        int hy = p / 57, hx = p - hy * 57;
        float a = bias;
#pragma unroll
        for (int ic = 0; ic < 3; ++ic)
#pragma unroll
          for (int kh = 0; kh < 3; ++kh) {
            const float* row = &x_s[ic * (19 * 116) + (2 * hy + kh) * 116 + 2 * hx];
            a = fmaf(row[0], wr[ic * 9 + kh * 3 + 0], a);
            a = fmaf(row[1], wr[ic * 9 + kh * 3 + 1], a);
            a = fmaf(row[2], wr[ic * 9 + kh * 3 + 2], a);
          }
        float v = fmaxf(a, 0.f);
        int hy_g = ty * 8 + hy, hx_g = tx * 56 + hx;
        if (hy_g >= 112 || hx_g >= 112) v = 0.f;
        h1_s[hc_l * 522 + hy * 58 + hx] = v;
      }
    }
    __syncthreads();
    for (int ic_l = 0; ic_l < 8; ++ic_l) {
#pragma unroll
      for (int kh = 0; kh < 3; ++kh)
#pragma unroll
        for (int kw = 0; kw < 3; ++kw) {
          const int k = (c * 8 + ic_l) * 9 + kh * 3 + kw;
          const float4 wA = *(const float4*)(w2t + k * 128 + ocg * 8);
          const float4 wB = *(const float4*)(w2t + k * 128 + ocg * 8 + 4);
          const float* hp = &h1_s[ic_l * 522 + kh * 58 + kw];
#pragma unroll
          for (int j = 0; j < 7; ++j) {
            float h = hp[pbase[j]];
            acc[j][0] = fmaf(wA.x, h, acc[j][0]);
            acc[j][1] = fmaf(wA.y, h, acc[j][1]);
            acc[j][2] = fmaf(wA.z, h, acc[j][2]);
            acc[j][3] = fmaf(wA.w, h, acc[j][3]);
            acc[j][4] = fmaf(wB.x, h, acc[j][4]);
            acc[j][5] = fmaf(wB.y, h, acc[j][5]);
            acc[j][6] = fmaf(wB.z, h, acc[j][6]);
            acc[j][7] = fmaf(wB.w, h, acc[j][7]);
          }
        }
    }
  }
  __syncthreads();
  float* red = x_s;
#pragma unroll
  for (int i = 0; i < 8; ++i) {
    float bb = b2[ocg * 8 + i];
    float t = 0.f;
#pragma unroll
    for (int j = 0; j < 7; ++j) t += fmaxf(acc[j][i] + bb, 0.f);
    red[posg * 129 + ocg * 8 + i] = t;
  }
  __syncthreads();
  if (tid < 128) {
    float t = 0.f;
#pragma unroll
    for (int pg = 0; pg < 16; ++pg) t += red[pg * 129 + tid];
    atomicAdd(&g[(e * 64 + b) * 128 + tid], t);
  }
}

extern "C" void kernel_launch(void* const* d_in, const int* in_sizes, int n_in,
                              void* d_out, int out_size, void* d_ws, size_t ws_size,
                              hipStream_t stream) {
  const float* x    = (const float*)d_in[0];
  const float* t_w1 = (const float*)d_in[1];
  const float* t_b1 = (const float*)d_in[2];
  const float* t_w2 = (const float*)d_in[3];
  const float* t_b2 = (const float*)d_in[4];
  const float* t_wf = (const float*)d_in[5];
  const float* t_bf = (const float*)d_in[6];
  const float* f_w1 = (const float*)d_in[7];
  const float* f_b1 = (const float*)d_in[8];
  const float* f_w2 = (const float*)d_in[9];
  const float* f_b2 = (const float*)d_in[10];
  const float* f_wf = (const float*)d_in[11];
  const float* f_bf = (const float*)d_in[12];
  float* out = (float*)d_out;
  char* ws = (char*)d_ws;

  if (ws_size >= WS_NEED) {
    float*  gbuf = (float*)(ws + G_OFF);
    ushort* h1   = (ushort*)(ws + H1_OFF);
    ushort* w2b  = (ushort*)(ws + W2B_OFF);
    float*  w1t  = (float*)(ws + W1T_OFF);
    hipMemsetAsync(gbuf, 0, 2 * 64 * 128 * sizeof(float), stream);
    prep_new<<<590, 256, 0, stream>>>(t_w2, f_w2, t_w1, f_w1, ws);
    conv1_cl<<<dim3(113, 64, 2), 256, 0, stream>>>(x, w1t, t_b1, f_b1, h1);
    conv2_mfma<<<dim3(28, 64, 2), 256, 0, stream>>>(h1, w2b, t_b2, f_b2, gbuf);
    finale<<<1, 64, 0, stream>>>(gbuf, t_wf, t_bf, f_wf, f_bf, out);
  } else {
    float* w2t = (float*)ws;
    float* g2  = (float*)(ws + 589824);
    hipMemsetAsync(g2, 0, 2 * 64 * 128 * sizeof(float), stream);
    transpose_w2<<<576, 256, 0, stream>>>(t_w2, f_w2, w2t);
    fused_expert<<<dim3(28, 64, 2), 256, 0, stream>>>(
        x, t_w1, t_b1, t_b2, f_w1, f_b1, f_b2, w2t, g2);
    finale<<<1, 64, 0, stream>>>(g2, t_wf, t_bf, f_wf, f_bf, out);
  }
}

// Round 5
// 336.507 us; speedup vs baseline: 10.9954x; 1.5885x over previous
//
#include <hip/hip_runtime.h>
#include <hip/hip_bf16.h>
#include <math.h>

// x [64,3,224,224] fp32; expert: conv3x3 s2 (3->64)+ReLU -> conv3x3 s2 (64->128)
// +ReLU -> GAP -> FC 128->2; blend on t softmax conf <= 0.9. Out: 129 floats.
// SAME s2: pad_lo=0, pad_hi=1 both convs.
//
// Round-5: conv2 A-operand pre-swizzled to MFMA-fragment-major (coalesced
// 1KB/wave loads); conv1 4 rows/block, 16B stores.
//
// ws layout (bytes):
//   W2B_OFF: ushort w2frag[2 term][2 e][8 octile][18 kc][64 lane][8]
//            oc = octile*16 + (lane&15); kk = kc*32 + (lane>>4)*8 + j
//            kk = kh*192 + kw*64 + ic
//   W1T_OFF: float  w1t[2 e][27 k][64 ch]   k = ic*9+kh*3+kw
//   G_OFF:   float  g[2 e][64 b][128 oc]
//   H1_OFF:  ushort h1[2 e][64 b][113 row][113 hx][64 ic] (row/col 112 = 0)

#define W2B_OFF   0ull
#define W1T_OFF   589824ull
#define G_OFF     603648ull
#define H1_OFF    669440ull
#define H1E_US    52301824ull   // 64*113*113*64
#define H1B_US    817216ull     // 113*113*64
#define WS_NEED   (H1_OFF + 2ull*H1E_US*2ull + 4096ull)

typedef __attribute__((ext_vector_type(8))) short bf16x8;
typedef __attribute__((ext_vector_type(4))) float f32x4;

__device__ inline ushort f2bf(float v) {
  __hip_bfloat16 h = __float2bfloat16(v);
  return *(ushort*)&h;
}
__device__ inline float bf2f(ushort u) {
  __hip_bfloat16 h = *(__hip_bfloat16*)&u;
  return __bfloat162float(h);
}

__global__ __launch_bounds__(256) void prep_new(
    const float* __restrict__ w2_t, const float* __restrict__ w2_f,
    const float* __restrict__ w1_t, const float* __restrict__ w1_f,
    char* __restrict__ ws) {
  int idx = blockIdx.x * 256 + threadIdx.x;
  ushort* w2frag = (ushort*)(ws + W2B_OFF);
  float* w1t = (float*)(ws + W1T_OFF);
  if (idx < 294912) {
    int j    = idx & 7;
    int lane = (idx >> 3) & 63;
    int t2   = idx >> 9;          // [0,576)
    int kc   = t2 % 18;
    int t3   = t2 / 18;           // [0,32)
    int octile = t3 & 7;
    int t4   = t3 >> 3;           // [0,4)
    int e    = t4 & 1;
    int term = t4 >> 1;
    int oc = octile * 16 + (lane & 15);
    int kk = kc * 32 + (lane >> 4) * 8 + j;
    int kh = kk / 192, r2 = kk - kh * 192, kw = r2 >> 6, ic = r2 & 63;
    const float* src = e ? w2_f : w2_t;
    float w = src[((oc * 64 + ic) * 3 + kh) * 3 + kw];
    ushort hi = f2bf(w);
    w2frag[idx] = term ? f2bf(w - bf2f(hi)) : hi;
  } else if (idx < 294912 + 3456) {
    int i2 = idx - 294912;
    int e = i2 / 1728;
    int r = i2 - e * 1728;
    int k = r >> 6, ch = r & 63;
    const float* src = e ? w1_f : w1_t;
    w1t[i2] = src[ch * 27 + k];
  }
}

// conv1: block = (row group of 4, b, e). Thread: chg=tid&7 (8 ch), pxg=tid>>3
// (4 hx). Stages x rows 8g..8g+8 parity-split once, computes 4 rows, 16B stores.
__global__ __launch_bounds__(256, 2) void conv1_cl(
    const float* __restrict__ x,
    const float* __restrict__ w1t_all,
    const float* __restrict__ b1_t, const float* __restrict__ b1_f,
    ushort* __restrict__ h1_all)
{
  const int gR  = blockIdx.x;   // rows 4g..4g+3 (g=28 -> zero row 112)
  const int b   = blockIdx.y;
  const int e   = blockIdx.z;
  const int tid = threadIdx.x;
  ushort* h1b = h1_all + (size_t)e * H1E_US + (size_t)b * H1B_US;

  __shared__ float x_s[3 * 9 * 232];   // [ic][xr_l][even 0..115 | odd 116..231]
  __shared__ float w1s[1728];          // [27][64]

  const float* w1t = w1t_all + e * 1728;
  const float* b1  = e ? b1_f : b1_t;
  for (int i = tid; i < 1728; i += 256) w1s[i] = w1t[i];

  const float* xb = x + (size_t)b * 150528;
  const int xr0 = 8 * gR;
  for (int i = tid; i < 3 * 9 * 113; i += 256) {
    int ic   = i / (9 * 113);
    int rem  = i - ic * (9 * 113);
    int xr_l = rem / 113;
    int col  = rem - xr_l * 113;
    int xr = xr0 + xr_l;
    float e0 = 0.f, o0 = 0.f;
    if (xr < 224 && col < 112) {
      const float2 p2 = *(const float2*)(xb + (ic * 224 + xr) * 224 + 2 * col);
      e0 = p2.x; o0 = p2.y;
    }
    x_s[(ic * 9 + xr_l) * 232 + col] = e0;
    x_s[(ic * 9 + xr_l) * 232 + 116 + col] = o0;
  }
  __syncthreads();

  const int chg = tid & 7;      // ch0 = chg*8
  const int pxg = tid >> 3;     // hx0 = pxg*4
  const int hx0 = pxg * 4;

  const float4 bA = *(const float4*)&b1[chg * 8];
  const float4 bB = *(const float4*)&b1[chg * 8 + 4];
  const float bv[8] = {bA.x, bA.y, bA.z, bA.w, bB.x, bB.y, bB.z, bB.w};

  for (int r = 0; r < 4; ++r) {
    const int row = 4 * gR + r;
    if (row > 112) break;
    float acc[8][4];
#pragma unroll
    for (int c = 0; c < 8; ++c)
#pragma unroll
      for (int j = 0; j < 4; ++j) acc[c][j] = 0.f;

    if (row < 112) {
#pragma unroll
      for (int ickr = 0; ickr < 9; ++ickr) {
        const int ic = ickr / 3, kr = ickr - 3 * ic;
        const float* xs = &x_s[(ic * 9 + 2 * r + kr) * 232];
        float he[5], ho[4];
        *(float4*)&he[0] = *(const float4*)&xs[hx0];
        he[4] = xs[hx0 + 4];
        *(float4*)&ho[0] = *(const float4*)&xs[116 + hx0];
        const float4 wa0 = *(const float4*)&w1s[(ickr * 3 + 0) * 64 + chg * 8];
        const float4 wa1 = *(const float4*)&w1s[(ickr * 3 + 0) * 64 + chg * 8 + 4];
        const float4 wb0 = *(const float4*)&w1s[(ickr * 3 + 1) * 64 + chg * 8];
        const float4 wb1 = *(const float4*)&w1s[(ickr * 3 + 1) * 64 + chg * 8 + 4];
        const float4 wc0 = *(const float4*)&w1s[(ickr * 3 + 2) * 64 + chg * 8];
        const float4 wc1 = *(const float4*)&w1s[(ickr * 3 + 2) * 64 + chg * 8 + 4];
        const float wa[8] = {wa0.x, wa0.y, wa0.z, wa0.w, wa1.x, wa1.y, wa1.z, wa1.w};
        const float wb[8] = {wb0.x, wb0.y, wb0.z, wb0.w, wb1.x, wb1.y, wb1.z, wb1.w};
        const float wc[8] = {wc0.x, wc0.y, wc0.z, wc0.w, wc1.x, wc1.y, wc1.z, wc1.w};
#pragma unroll
        for (int j = 0; j < 4; ++j)
#pragma unroll
          for (int c = 0; c < 8; ++c) {
            acc[c][j] = fmaf(wa[c], he[j], acc[c][j]);
            acc[c][j] = fmaf(wb[c], ho[j], acc[c][j]);
            acc[c][j] = fmaf(wc[c], he[j + 1], acc[c][j]);
          }
      }
    }

#pragma unroll
    for (int j = 0; j < 4; ++j) {
      const int hx = hx0 + j;
      if (hx < 113) {
        const bool live = (hx < 112) && (row < 112);
        ushort v[8];
#pragma unroll
        for (int c = 0; c < 8; ++c)
          v[c] = f2bf(live ? fmaxf(acc[c][j] + bv[c], 0.f) : 0.f);
        uint4 u;
        u.x = (uint)v[0] | ((uint)v[1] << 16);
        u.y = (uint)v[2] | ((uint)v[3] << 16);
        u.z = (uint)v[4] | ((uint)v[5] << 16);
        u.w = (uint)v[6] | ((uint)v[7] << 16);
        *(uint4*)&h1b[((size_t)(row * 113 + hx)) * 64 + chg * 8] = u;
      }
    }
  }
}

// conv2 via MFMA. Block (T=row-pair 0..27, b, e), 4 waves.
// Wave w: octiles {2w, 2w+1} (32 oc), 7 N-tiles (8px x 2rows = 112 px exact).
__global__ __launch_bounds__(256) void conv2_mfma(
    const ushort* __restrict__ h1_all,
    const ushort* __restrict__ w2frag,
    const float* __restrict__ b2_t, const float* __restrict__ b2_f,
    float* __restrict__ g)
{
  const int T = blockIdx.x;
  const int b = blockIdx.y;
  const int e = blockIdx.z;
  const int tid  = threadIdx.x;
  const int w    = tid >> 6;
  const int lane = tid & 63;
  const ushort* h1b = h1_all + (size_t)e * H1E_US + (size_t)b * H1B_US;
  const float* b2 = e ? b2_f : b2_t;

  __shared__ ushort hs[2 * 113 * 72];   // 32.5 KB

  const int q   = lane >> 4;
  const int n   = lane & 15;
  const int pxl = lane & 7;
  const int rl  = (lane >> 3) & 1;

  f32x4 acc[2][7];
#pragma unroll
  for (int mt = 0; mt < 2; ++mt)
#pragma unroll
    for (int nt = 0; nt < 7; ++nt) acc[mt][nt] = (f32x4){0.f, 0.f, 0.f, 0.f};

  for (int kh = 0; kh < 3; ++kh) {
    __syncthreads();
    for (int i = tid; i < 1808; i += 256) {
      int rs = (i >= 904) ? 1 : 0;
      int rem = i - rs * 904;
      int hx = rem >> 3, gq = rem & 7;
      int R = 4 * T + kh + 2 * rs;
      *(bf16x8*)&hs[(rs * 113 + hx) * 72 + 8 * gq] =
          *(const bf16x8*)&h1b[((size_t)(R * 113 + hx)) * 64 + 8 * gq];
    }
    __syncthreads();
#pragma unroll
    for (int kw = 0; kw < 3; ++kw) {
#pragma unroll
      for (int icc = 0; icc < 2; ++icc) {
        const int kc = kh * 6 + kw * 2 + icc;
        const int icoff = icc * 32 + 8 * q;
        bf16x8 bf[7];
#pragma unroll
        for (int nt = 0; nt < 7; ++nt) {
          int hx = 2 * (8 * nt + pxl) + kw;
          bf[nt] = *(const bf16x8*)&hs[(rl * 113 + hx) * 72 + icoff];
        }
#pragma unroll
        for (int term = 0; term < 2; ++term) {
#pragma unroll
          for (int mt = 0; mt < 2; ++mt) {
            const int octile = 2 * w + mt;
            bf16x8 af = *(const bf16x8*)
                &w2frag[((size_t)(((term * 2 + e) * 8 + octile) * 18 + kc)) * 512
                        + lane * 8];
#pragma unroll
            for (int nt = 0; nt < 7; ++nt)
              acc[mt][nt] = __builtin_amdgcn_mfma_f32_16x16x32_bf16(
                  af, bf[nt], acc[mt][nt], 0, 0, 0);
          }
        }
      }
    }
  }

#pragma unroll
  for (int mt = 0; mt < 2; ++mt) {
#pragma unroll
    for (int reg = 0; reg < 4; ++reg) {
      const int oc = 32 * w + 16 * mt + 4 * q + reg;
      const float bias = b2[oc];
      float s = 0.f;
#pragma unroll
      for (int nt = 0; nt < 7; ++nt) s += fmaxf(acc[mt][nt][reg] + bias, 0.f);
      s += __shfl_xor(s, 1);
      s += __shfl_xor(s, 2);
      s += __shfl_xor(s, 4);
      s += __shfl_xor(s, 8);
      if (n == 0) atomicAdd(&g[((size_t)e * 64 + b) * 128 + oc], s);
    }
  }
}

__global__ __launch_bounds__(64) void finale(
    const float* __restrict__ g,
    const float* __restrict__ t_wf, const float* __restrict__ t_bf,
    const float* __restrict__ f_wf, const float* __restrict__ f_bf,
    float* __restrict__ out)
{
  const int b = threadIdx.x;
  const float inv = 1.0f / 3136.0f;
  const float* gt = g + b * 128;
  const float* gf = g + (64 + b) * 128;
  float lt0 = t_bf[0], lt1 = t_bf[1];
  float lf0 = f_bf[0], lf1 = f_bf[1];
  for (int k = 0; k < 128; ++k) {
    float vt = gt[k] * inv;
    float vf = gf[k] * inv;
    lt0 = fmaf(vt, t_wf[2 * k],     lt0);
    lt1 = fmaf(vt, t_wf[2 * k + 1], lt1);
    lf0 = fmaf(vf, f_wf[2 * k],     lf0);
    lf1 = fmaf(vf, f_wf[2 * k + 1], lf1);
  }
  float m  = fmaxf(lt0, lt1);
  float e0 = expf(lt0 - m), e1 = expf(lt1 - m);
  float conf = fmaxf(e0, e1) / (e0 + e1);
  bool use2 = (conf <= 0.9f);
  out[2 * b]     = use2 ? 0.7f * lt0 + 0.3f * lf0 : lt0;
  out[2 * b + 1] = use2 ? 0.7f * lt1 + 0.3f * lf1 : lt1;
  unsigned long long mask = __ballot(use2);
  if (b == 0) out[128] = (float)__popcll(mask) * (1.0f / 64.0f);
}

// ---------------- fallback (ws too small): round-1 fused fp32 ----------------
__global__ __launch_bounds__(256) void transpose_w2(
    const float* __restrict__ w2_t, const float* __restrict__ w2_f,
    float* __restrict__ w2t) {
  int idx = blockIdx.x * 256 + threadIdx.x;
  int e = idx / 73728;
  int r = idx - e * 73728;
  int k = r >> 7, oc = r & 127;
  const float* src = e ? w2_f : w2_t;
  w2t[idx] = src[oc * 576 + k];
}

__global__ __launch_bounds__(256, 3) void fused_expert(
    const float* __restrict__ x,
    const float* __restrict__ w1_t, const float* __restrict__ b1_t,
    const float* __restrict__ b2_t,
    const float* __restrict__ w1_f, const float* __restrict__ b1_f,
    const float* __restrict__ b2_f,
    const float* __restrict__ w2t_all, float* __restrict__ g)
{
  const int tile = blockIdx.x, b = blockIdx.y, e = blockIdx.z;
  const int ty = tile >> 1, tx = tile & 1;
  const float* w1  = e ? w1_f : w1_t;
  const float* b1  = e ? b1_f : b1_t;
  const float* b2  = e ? b2_f : b2_t;
  const float* w2t = w2t_all + e * 73728;
  __shared__ float x_s[3 * 19 * 116];
  __shared__ float h1_s[8 * 9 * 58];
  __shared__ float w1_s[1728];
  const int tid = threadIdx.x;
  {
    const float* xb = x + (size_t)b * 150528;
    const int xr0 = ty * 16, xc0 = tx * 112;
    for (int idx = tid; idx < 3 * 19 * 116; idx += 256) {
      int ic = idx / (19 * 116);
      int rem = idx - ic * (19 * 116);
      int r = rem / 116, cc = rem - r * 116;
      int xr = xr0 + r, xc = xc0 + cc;
      float v = 0.f;
      if (xr < 224 && xc < 224 && cc < 115) v = xb[(ic * 224 + xr) * 224 + xc];
      x_s[idx] = v;
    }
    for (int idx = tid; idx < 1728; idx += 256) w1_s[idx] = w1[idx];
  }
  const int ocg = tid >> 4, posg = tid & 15;
  int pbase[7];
#pragma unroll
  for (int j = 0; j < 7; ++j) {
    int p = posg + 16 * j, py = p / 28, px = p - py * 28;
    pbase[j] = py * 2 * 58 + px * 2;
  }
  float acc[7][8];
#pragma unroll
  for (int j = 0; j < 7; ++j)
#pragma unroll
    for (int i = 0; i < 8; ++i) acc[j][i] = 0.f;
  const int hc_l = tid >> 5, l32 = tid & 31;
  for (int c = 0; c < 8; ++c) {
    __syncthreads();
    {
      const int hc = c * 8 + hc_l;
      const float bias = b1[hc];
      float wr[27];
#pragma unroll
      for (int qq = 0; qq < 27; ++qq) wr[qq] = w1_s[hc * 27 + qq];
      for (int p = l32; p < 513; p += 32) {
        int hy = p / 57, hx = p - hy * 57;
        float a = bias;
#pragma unroll
        for (int ic = 0; ic < 3; ++ic)
#pragma unroll
          for (int kh = 0; kh < 3; ++kh) {
            const float* row = &x_s[ic * (19 * 116) + (2 * hy + kh) * 116 + 2 * hx];
            a = fmaf(row[0], wr[ic * 9 + kh * 3 + 0], a);
            a = fmaf(row[1], wr[ic * 9 + kh * 3 + 1], a);
            a = fmaf(row[2], wr[ic * 9 + kh * 3 + 2], a);
          }
        float v = fmaxf(a, 0.f);
        int hy_g = ty * 8 + hy, hx_g = tx * 56 + hx;
        if (hy_g >= 112 || hx_g >= 112) v = 0.f;
        h1_s[hc_l * 522 + hy * 58 + hx] = v;
      }
    }
    __syncthreads();
    for (int ic_l = 0; ic_l < 8; ++ic_l) {
#pragma unroll
      for (int kh = 0; kh < 3; ++kh)
#pragma unroll
        for (int kw = 0; kw < 3; ++kw) {
          const int k = (c * 8 + ic_l) * 9 + kh * 3 + kw;
          const float4 wA = *(const float4*)(w2t + k * 128 + ocg * 8);
          const float4 wB = *(const float4*)(w2t + k * 128 + ocg * 8 + 4);
          const float* hp = &h1_s[ic_l * 522 + kh * 58 + kw];
#pragma unroll
          for (int j = 0; j < 7; ++j) {
            float h = hp[pbase[j]];
            acc[j][0] = fmaf(wA.x, h, acc[j][0]);
            acc[j][1] = fmaf(wA.y, h, acc[j][1]);
            acc[j][2] = fmaf(wA.z, h, acc[j][2]);
            acc[j][3] = fmaf(wA.w, h, acc[j][3]);
            acc[j][4] = fmaf(wB.x, h, acc[j][4]);
            acc[j][5] = fmaf(wB.y, h, acc[j][5]);
            acc[j][6] = fmaf(wB.z, h, acc[j][6]);
            acc[j][7] = fmaf(wB.w, h, acc[j][7]);
          }
        }
    }
  }
  __syncthreads();
  float* red = x_s;
#pragma unroll
  for (int i = 0; i < 8; ++i) {
    float bb = b2[ocg * 8 + i];
    float t = 0.f;
#pragma unroll
    for (int j = 0; j < 7; ++j) t += fmaxf(acc[j][i] + bb, 0.f);
    red[posg * 129 + ocg * 8 + i] = t;
  }
  __syncthreads();
  if (tid < 128) {
    float t = 0.f;
#pragma unroll
    for (int pg = 0; pg < 16; ++pg) t += red[pg * 129 + tid];
    atomicAdd(&g[(e * 64 + b) * 128 + tid], t);
  }
}

extern "C" void kernel_launch(void* const* d_in, const int* in_sizes, int n_in,
                              void* d_out, int out_size, void* d_ws, size_t ws_size,
                              hipStream_t stream) {
  const float* x    = (const float*)d_in[0];
  const float* t_w1 = (const float*)d_in[1];
  const float* t_b1 = (const float*)d_in[2];
  const float* t_w2 = (const float*)d_in[3];
  const float* t_b2 = (const float*)d_in[4];
  const float* t_wf = (const float*)d_in[5];
  const float* t_bf = (const float*)d_in[6];
  const float* f_w1 = (const float*)d_in[7];
  const float* f_b1 = (const float*)d_in[8];
  const float* f_w2 = (const float*)d_in[9];
  const float* f_b2 = (const float*)d_in[10];
  const float* f_wf = (const float*)d_in[11];
  const float* f_bf = (const float*)d_in[12];
  float* out = (float*)d_out;
  char* ws = (char*)d_ws;

  if (ws_size >= WS_NEED) {
    float*  gbuf   = (float*)(ws + G_OFF);
    ushort* h1     = (ushort*)(ws + H1_OFF);
    ushort* w2frag = (ushort*)(ws + W2B_OFF);
    float*  w1t    = (float*)(ws + W1T_OFF);
    hipMemsetAsync(gbuf, 0, 2 * 64 * 128 * sizeof(float), stream);
    prep_new<<<1166, 256, 0, stream>>>(t_w2, f_w2, t_w1, f_w1, ws);
    conv1_cl<<<dim3(29, 64, 2), 256, 0, stream>>>(x, w1t, t_b1, f_b1, h1);
    conv2_mfma<<<dim3(28, 64, 2), 256, 0, stream>>>(h1, w2frag, t_b2, f_b2, gbuf);
    finale<<<1, 64, 0, stream>>>(gbuf, t_wf, t_bf, f_wf, f_bf, out);
  } else {
    float* w2t = (float*)ws;
    float* g2  = (float*)(ws + 589824);
    hipMemsetAsync(g2, 0, 2 * 64 * 128 * sizeof(float), stream);
    transpose_w2<<<576, 256, 0, stream>>>(t_w2, f_w2, w2t);
    fused_expert<<<dim3(28, 64, 2), 256, 0, stream>>>(
        x, t_w1, t_b1, t_b2, f_w1, f_b1, f_b2, w2t, g2);
    finale<<<1, 64, 0, stream>>>(g2, t_wf, t_bf, f_wf, f_bf, out);
  }
}